// Round 1
// baseline (302.997 us; speedup 1.0000x reference)
//
#include <hip/hip_runtime.h>
#include <hip/hip_bf16.h>

#define B_ 64
#define S_ 1024
#define H_ 256
#define E_ 256
#define C_ 16          // scan chunks per sequence
#define CS_ 64         // rows per chunk

typedef __attribute__((ext_vector_type(8))) __bf16 bf16x8;
typedef __attribute__((ext_vector_type(4))) __bf16 bf16x4;
typedef __attribute__((ext_vector_type(4))) float f32x4;

// ---------------- K0: one-time Wb fp32 -> bf16 (row-major [E][H]) ----------------
__global__ __launch_bounds__(256) void k0_wb_bf16(const float* __restrict__ Wb,
                                                  __bf16* __restrict__ WbBf) {
    int i = blockIdx.x * 256 + threadIdx.x;
    float4 v = ((const float4*)Wb)[i];
    bf16x4 b;
    b[0] = (__bf16)v.x; b[1] = (__bf16)v.y;
    b[2] = (__bf16)v.z; b[3] = (__bf16)v.w;
    ((bf16x4*)WbBf)[i] = b;
}

// ---------------- K2': w + GEMM(tanh)*w*embed + WITHIN-CHUNK SUFFIX + chunk totals
// Block = 64 rows (one chunk), 4 waves. Wave wv owns rows [wv*16, wv*16+16), all E.
// No LDS staging for B: fragments are read straight from L2-resident bf16 Wb.
__global__ __launch_bounds__(256, 4) void k2_fused(
        const float* __restrict__ alpha, const float* __restrict__ beta,
        const float* __restrict__ embed, const float* __restrict__ mask,
        const __bf16* __restrict__ WbBf, const float* __restrict__ bb,
        const float* __restrict__ Wa,    const float* __restrict__ ba,
        float* __restrict__ w, float* __restrict__ chunkTot, float* __restrict__ t) {
    __shared__ float red[4 * E_];   // per-wave e-column totals
    __shared__ float wsh[CS_];

    const int tid = threadIdx.x;
    const int wv = tid >> 6, lane = tid & 63;
    const int l15 = lane & 15, q = lane >> 4;
    const int m0 = blockIdx.x * CS_;

    // ---- phase W: 4 lanes per row, all 64 rows in parallel ----
    {
        const int pr = tid >> 2, pc = tid & 3;
        const int m = m0 + pr;
        const float4* ar = (const float4*)(alpha + (size_t)m * H_ + pc * 64);
        const float4* wr = (const float4*)(Wa + pc * 64);
        float p = 0.f;
        #pragma unroll
        for (int i = 0; i < 16; ++i) {
            float4 a = ar[i], v = wr[i];
            p += a.x * v.x + a.y * v.y + a.z * v.z + a.w * v.w;
        }
        p += __shfl_xor(p, 1, 64);
        p += __shfl_xor(p, 2, 64);
        if (pc == 0) {
            float wm = __expf(p + ba[0]) * mask[m];
            wsh[pr] = wm;
            w[m] = wm;
        }
    }
    __syncthreads();

    // ---- GEMM main loop: barrier-free, B-fragments direct from L2 ----
    const float*  Arow = beta + (size_t)(m0 + wv * 16 + l15) * H_ + q * 8;
    const __bf16* Brow = WbBf + (size_t)l15 * H_ + q * 8;
    f32x4 acc[16];
    #pragma unroll
    for (int i = 0; i < 16; ++i) acc[i] = (f32x4){0.f, 0.f, 0.f, 0.f};

    #pragma unroll 2
    for (int kc = 0; kc < 8; ++kc) {
        float4 a0 = *(const float4*)(Arow + kc * 32);
        float4 a1 = *(const float4*)(Arow + kc * 32 + 4);
        bf16x8 af;
        af[0] = (__bf16)a0.x; af[1] = (__bf16)a0.y;
        af[2] = (__bf16)a0.z; af[3] = (__bf16)a0.w;
        af[4] = (__bf16)a1.x; af[5] = (__bf16)a1.y;
        af[6] = (__bf16)a1.z; af[7] = (__bf16)a1.w;
        #pragma unroll
        for (int et = 0; et < 16; ++et) {
            bf16x8 bf = *(const bf16x8*)(Brow + (size_t)et * 16 * H_ + kc * 32);
            acc[et] = __builtin_amdgcn_mfma_f32_16x16x32_bf16(af, bf, acc[et], 0, 0, 0);
        }
    }

    // ---- epilogue: tanh, * w * embed, then within-chunk suffix scan ----
    // C/D layout: col(e) = lane&15, local row = q*4 + r
    float wmr[4];
    #pragma unroll
    for (int r = 0; r < 4; ++r) wmr[r] = wsh[wv * 16 + q * 4 + r];

    #pragma unroll
    for (int et = 0; et < 16; ++et) {
        const int e = et * 16 + l15;
        const float bbe = bb[e];
        float tv[4];
        #pragma unroll
        for (int r = 0; r < 4; ++r) {
            const int m = m0 + wv * 16 + q * 4 + r;
            float x = acc[et][r] + bbe;
            x = fminf(fmaxf(x, -15.f), 15.f);
            float ex = __expf(2.f * x);
            float th = (ex - 1.f) / (ex + 1.f);
            tv[r] = wmr[r] * th * embed[(size_t)m * E_ + e];
        }
        // suffix within this lane's 4 rows
        float s3 = tv[3];
        float s2 = tv[2] + s3;
        float s1 = tv[1] + s2;
        float s0 = tv[0] + s1;
        float g  = s0;                              // this q-group's 4-row total
        // exclusive suffix across the 4 q-groups (rows q*4.. within wave)
        float g1 = __shfl_down(g, 16, 64);
        float g2 = __shfl_down(g, 32, 64);
        float g3 = __shfl_down(g, 48, 64);
        float addG = (q < 3 ? g1 : 0.f) + (q < 2 ? g2 : 0.f) + (q < 1 ? g3 : 0.f);
        if (q == 0) red[wv * E_ + e] = g + addG;    // wave total for column e
        acc[et][0] = s0 + addG;                     // reuse acc for suffix values
        acc[et][1] = s1 + addG;
        acc[et][2] = s2 + addG;
        acc[et][3] = s3 + addG;
    }
    __syncthreads();

    // add totals of later waves; store within-chunk suffix t'
    #pragma unroll
    for (int et = 0; et < 16; ++et) {
        const int e = et * 16 + l15;
        float wa = 0.f;
        #pragma unroll
        for (int d = 1; d < 4; ++d)
            if (wv + d < 4) wa += red[(wv + d) * E_ + e];
        #pragma unroll
        for (int r = 0; r < 4; ++r) {
            const int m = m0 + wv * 16 + q * 4 + r;
            t[(size_t)m * E_ + e] = acc[et][r] + wa;
        }
    }
    const float ct = red[tid] + red[E_ + tid] + red[2 * E_ + tid] + red[3 * E_ + tid];
    chunkTot[(size_t)blockIdx.x * E_ + tid] = ct;
}

// ---------------- K3b: chunk-offset suffix scan + full inverse denominators ----
__global__ __launch_bounds__(256) void k3b_scan(
        const float* __restrict__ w, const float* __restrict__ chunkTot,
        float* __restrict__ chunkOff, float* __restrict__ invDen) {
    const int tid = threadIdx.x;
    const int b = blockIdx.x;

    // exclusive suffix over chunks for (b, e=tid)
    float acc = 0.f;
    #pragma unroll
    for (int c = C_ - 1; c >= 0; --c) {
        chunkOff[((size_t)b * C_ + c) * E_ + tid] = acc;
        acc += chunkTot[((size_t)b * C_ + c) * E_ + tid];
    }

    // inclusive suffix over s of w -> invDen[b,s] = 1/(suf + 1e-10)
    float4 w4 = *(const float4*)(w + b * S_ + tid * 4);
    float tot = w4.x + w4.y + w4.z + w4.w;
    int lane = tid & 63, wv = tid >> 6;
    float suf = tot;
    #pragma unroll
    for (int off = 1; off < 64; off <<= 1) {
        float o = __shfl_down(suf, off, 64);
        if (lane + off < 64) suf += o;
    }
    __shared__ float wsum[4];
    if (lane == 0) wsum[wv] = suf;       // lane0 inclusive suffix == wave total
    __syncthreads();
    float waveOff = 0.f;
    for (int j = wv + 1; j < 4; ++j) waveOff += wsum[j];
    float after = (suf - tot) + waveOff; // exclusive suffix beyond this thread
    float s3 = w4.w + after;
    float s2 = w4.z + s3;
    float s1 = w4.y + s2;
    float s0 = w4.x + s1;
    float4 inv = { 1.f / (s0 + 1e-10f), 1.f / (s1 + 1e-10f),
                   1.f / (s2 + 1e-10f), 1.f / (s3 + 1e-10f) };
    *(float4*)(invDen + b * S_ + tid * 4) = inv;
}

// ---------------- K3c: pure streaming finish: t = (t' + chunkOff) * invDen ----
__global__ __launch_bounds__(256) void k3c_finish(
        float* __restrict__ t, const float* __restrict__ chunkOff,
        const float* __restrict__ invDen) {
    const int blk = blockIdx.x;              // b*16 + c
    const int b = blk >> 4, c = blk & 15;
    const int tid = threadIdx.x;
    float4* tp = (float4*)(t + ((size_t)b * S_ + c * CS_) * E_);
    const float4* co = (const float4*)(chunkOff + (size_t)blk * E_);
    const float* iv = invDen + b * S_ + c * CS_;
    #pragma unroll
    for (int i = 0; i < 16; ++i) {
        const int idx = i * 256 + tid;       // 0..4095 float4s in this chunk
        const int row = idx >> 6;            // 64 float4 per e-row
        const int e4 = idx & 63;
        float4 v = tp[idx];
        float4 o = co[e4];
        float s = iv[row];
        v.x = (v.x + o.x) * s;
        v.y = (v.y + o.y) * s;
        v.z = (v.z + o.z) * s;
        v.w = (v.w + o.w) * s;
        tp[idx] = v;
    }
}

extern "C" void kernel_launch(void* const* d_in, const int* in_sizes, int n_in,
                              void* d_out, int out_size, void* d_ws, size_t ws_size,
                              hipStream_t stream) {
    const float* alpha = (const float*)d_in[0];
    const float* beta  = (const float*)d_in[1];
    const float* embed = (const float*)d_in[2];
    const float* mask  = (const float*)d_in[3];
    const float* Wb    = (const float*)d_in[4];
    const float* bb    = (const float*)d_in[5];
    const float* Wa    = (const float*)d_in[6];
    const float* ba    = (const float*)d_in[7];

    float* t = (float*)d_out;  // t' lives in d_out; finished in place

    char* ws = (char*)d_ws;
    float*  w        = (float*)ws;                                  // 256 KB
    float*  chunkTot = (float*)(ws + (256 << 10));                  // 1 MB
    float*  chunkOff = (float*)(ws + (256 << 10) + (1 << 20));      // 1 MB
    float*  invDen   = (float*)(ws + (256 << 10) + (2 << 20));      // 256 KB
    __bf16* WbBf     = (__bf16*)(ws + (512 << 10) + (2 << 20));     // 128 KB

    k0_wb_bf16<<<E_ * H_ / 1024, 256, 0, stream>>>(Wb, WbBf);
    k2_fused<<<B_ * C_, 256, 0, stream>>>(alpha, beta, embed, mask, WbBf, bb, Wa, ba,
                                          w, chunkTot, t);
    k3b_scan<<<B_, 256, 0, stream>>>(w, chunkTot, chunkOff, invDen);
    k3c_finish<<<B_ * C_, 256, 0, stream>>>(t, chunkOff, invDen);
}

// Round 2
// 262.642 us; speedup vs baseline: 1.1537x; 1.1537x over previous
//
#include <hip/hip_runtime.h>
#include <hip/hip_bf16.h>
#include <hip/hip_cooperative_groups.h>

namespace cg = cooperative_groups;

#define B_ 64
#define S_ 1024
#define H_ 256
#define E_ 256
#define C_ 16          // scan chunks per sequence
#define CS_ 64         // rows per chunk

#define LDSB_STRIDE 40 // bf16 per e-row in LDS (80B stride -> 2-way conflicts only)

typedef __attribute__((ext_vector_type(8))) __bf16 bf16x8;
typedef __attribute__((ext_vector_type(4))) __bf16 bf16x4;
typedef __attribute__((ext_vector_type(4))) float f32x4;

// ---------------- K0: one-time Wb fp32 -> bf16 (row-major [E][H]) ----------------
__global__ __launch_bounds__(256) void k0_wb_bf16(const float* __restrict__ Wb,
                                                  __bf16* __restrict__ WbBf) {
    int i = blockIdx.x * 256 + threadIdx.x;
    float4 v = ((const float4*)Wb)[i];
    bf16x4 bv;
    bv[0] = (__bf16)v.x; bv[1] = (__bf16)v.y;
    bv[2] = (__bf16)v.z; bv[3] = (__bf16)v.w;
    ((bf16x4*)WbBf)[i] = bv;
}

// ---------------- fused kernel: w + GEMM(tanh)*w*embed + chunk suffix
//                  [COOP: + grid.sync + cross-chunk offsets + final scale] ------
// Block = 64 rows (one chunk), 4 waves. Wave wv owns rows [wv*16, wv*16+16), all E.
template <bool COOP>
__global__ __launch_bounds__(256, 4) void k2_main(
        const float* __restrict__ alpha, const float* __restrict__ beta,
        const float* __restrict__ embed, const float* __restrict__ mask,
        const __bf16* __restrict__ WbBf, const float* __restrict__ bb,
        const float* __restrict__ Wa,    const float* __restrict__ ba,
        float* __restrict__ chunkTot, float* __restrict__ wChunkSum,
        float* __restrict__ w, float* __restrict__ t) {
    __shared__ __bf16 ldsB[E_ * LDSB_STRIDE];   // 20 KB
    __shared__ float red[4 * E_];               // 4 KB
    __shared__ float wsh[CS_];
    __shared__ float wsuf[CS_];

    const int tid = threadIdx.x;
    const int wv = tid >> 6, lane = tid & 63;
    const int l15 = lane & 15, q = lane >> 4;
    const int blk = blockIdx.x;
    const int bat = blk >> 4, c = blk & 15;
    const int m0 = blk * CS_;

    // ---- phase W: 4 lanes per row, all 64 rows in parallel ----
    {
        const int pr = tid >> 2, pc = tid & 3;
        const int m = m0 + pr;
        const float4* ar = (const float4*)(alpha + (size_t)m * H_ + pc * 64);
        const float4* wr = (const float4*)(Wa + pc * 64);
        float p = 0.f;
        #pragma unroll
        for (int i = 0; i < 16; ++i) {
            float4 a = ar[i], v = wr[i];
            p += a.x * v.x + a.y * v.y + a.z * v.z + a.w * v.w;
        }
        p += __shfl_xor(p, 1, 64);
        p += __shfl_xor(p, 2, 64);
        if (pc == 0) {
            float wm = __expf(p + ba[0]) * mask[m];
            wsh[pr] = wm;
            if constexpr (!COOP) w[m] = wm;
        }
    }
    __syncthreads();
    if constexpr (COOP) {
        // per-chunk w total (for cross-chunk denominator tails after grid sync)
        if (tid < 64) {
            float v = wsh[tid];
            #pragma unroll
            for (int off = 32; off; off >>= 1) v += __shfl_xor(v, off, 64);
            if (tid == 0) wChunkSum[blk] = v;
        }
    }

    // ---- GEMM main loop: LDS-staged bf16 Wb (pre-converted by k0) ----
    const float* Arow = beta + (size_t)(m0 + wv * 16 + l15) * H_ + q * 8;
    f32x4 acc[16];
    #pragma unroll
    for (int i = 0; i < 16; ++i) acc[i] = (f32x4){0.f, 0.f, 0.f, 0.f};

    const int se = tid >> 2;          // e-row within 64-row pass group
    const int sk = (tid & 3) * 8;     // k-offset 0,8,16,24

    for (int kc = 0; kc < 8; ++kc) {
        // issue A loads early (independent of LDS)
        float4 a0 = *(const float4*)(Arow + kc * 32);
        float4 a1 = *(const float4*)(Arow + kc * 32 + 4);

        // stage WbBf chunk [256e][32k] bf16 -> LDS (no conversion needed)
        #pragma unroll
        for (int pass = 0; pass < 4; ++pass) {
            int e = pass * 64 + se;
            bf16x8 bv = *(const bf16x8*)(WbBf + (size_t)e * H_ + kc * 32 + sk);
            *(bf16x8*)(ldsB + e * LDSB_STRIDE + sk) = bv;
        }
        __syncthreads();

        bf16x8 af;
        af[0] = (__bf16)a0.x; af[1] = (__bf16)a0.y;
        af[2] = (__bf16)a0.z; af[3] = (__bf16)a0.w;
        af[4] = (__bf16)a1.x; af[5] = (__bf16)a1.y;
        af[6] = (__bf16)a1.z; af[7] = (__bf16)a1.w;
        #pragma unroll
        for (int et = 0; et < 16; ++et) {
            bf16x8 bf = *(const bf16x8*)(ldsB + (et * 16 + l15) * LDSB_STRIDE + q * 8);
            acc[et] = __builtin_amdgcn_mfma_f32_16x16x32_bf16(af, bf, acc[et], 0, 0, 0);
        }
        __syncthreads();
    }

    // ---- epilogue: tanh, * w * embed, within-chunk suffix scan (t' in regs) ----
    // C/D layout: col(e) = lane&15, local row = q*4 + r
    float wmr[4];
    #pragma unroll
    for (int r = 0; r < 4; ++r) wmr[r] = wsh[wv * 16 + q * 4 + r];

    #pragma unroll
    for (int et = 0; et < 16; ++et) {
        const int e = et * 16 + l15;
        const float bbe = bb[e];
        float tv[4];
        #pragma unroll
        for (int r = 0; r < 4; ++r) {
            const int m = m0 + wv * 16 + q * 4 + r;
            float x = acc[et][r] + bbe;
            x = fminf(fmaxf(x, -15.f), 15.f);
            float ex = __expf(2.f * x);
            float th = (ex - 1.f) / (ex + 1.f);
            tv[r] = wmr[r] * th * embed[(size_t)m * E_ + e];
        }
        // suffix within this lane's 4 rows
        float s3 = tv[3];
        float s2 = tv[2] + s3;
        float s1 = tv[1] + s2;
        float s0 = tv[0] + s1;
        float g  = s0;                              // this q-group's 4-row total
        float g1 = __shfl_down(g, 16, 64);
        float g2 = __shfl_down(g, 32, 64);
        float g3 = __shfl_down(g, 48, 64);
        float addG = (q < 3 ? g1 : 0.f) + (q < 2 ? g2 : 0.f) + (q < 1 ? g3 : 0.f);
        if (q == 0) red[wv * E_ + e] = g + addG;    // wave total for column e
        acc[et][0] = s0 + addG;
        acc[et][1] = s1 + addG;
        acc[et][2] = s2 + addG;
        acc[et][3] = s3 + addG;
    }
    __syncthreads();

    // chunk totals; fold later-wave offsets into acc (t' complete in registers)
    const float ct = red[tid] + red[E_ + tid] + red[2 * E_ + tid] + red[3 * E_ + tid];
    chunkTot[(size_t)blk * E_ + tid] = ct;
    #pragma unroll
    for (int et = 0; et < 16; ++et) {
        const int e = et * 16 + l15;
        float wa = 0.f;
        if (wv < 3) wa += red[(wv + 1) * E_ + e];
        if (wv < 2) wa += red[(wv + 2) * E_ + e];
        if (wv < 1) wa += red[(wv + 3) * E_ + e];
        acc[et][0] += wa; acc[et][1] += wa;
        acc[et][2] += wa; acc[et][3] += wa;
    }

    if constexpr (!COOP) {
        // fallback path: write t' and let k3b/k3c finish
        #pragma unroll
        for (int et = 0; et < 16; ++et) {
            const int e = et * 16 + l15;
            #pragma unroll
            for (int r = 0; r < 4; ++r) {
                const int m = m0 + wv * 16 + q * 4 + r;
                t[(size_t)m * E_ + e] = acc[et][r];
            }
        }
        return;
    } else {
        __threadfence();
        cg::this_grid().sync();
        __threadfence();

        // (a) cross-chunk per-e offsets (suffix of chunkTot over later chunks)
        float off = 0.f;
        for (int cc = c + 1; cc < C_; ++cc)
            off += chunkTot[((size_t)(bat * C_ + cc)) * E_ + tid];
        red[tid] = off;   // safe: grid sync block-synced; red readers all done

        // (b) w tail over later chunks (uniform -> scalar loads)
        float wtail = 0.f;
        for (int cc = c + 1; cc < C_; ++cc)
            wtail += wChunkSum[bat * C_ + cc];

        // (c) within-chunk inclusive suffix of wsh -> wsuf (Hillis-Steele)
        if (tid < 64) wsuf[tid] = wsh[tid];
        __syncthreads();
        for (int d = 1; d < 64; d <<= 1) {
            float v = 0.f;
            if (tid < 64 && tid + d < 64) v = wsuf[tid + d];
            __syncthreads();
            if (tid < 64) wsuf[tid] += v;
            __syncthreads();
        }

        float inv[4];
        #pragma unroll
        for (int r = 0; r < 4; ++r)
            inv[r] = 1.f / (wsuf[wv * 16 + q * 4 + r] + wtail + 1e-10f);

        // (d) final output, written once
        #pragma unroll
        for (int et = 0; et < 16; ++et) {
            const int e = et * 16 + l15;
            const float oe = red[e];
            #pragma unroll
            for (int r = 0; r < 4; ++r) {
                const int m = m0 + wv * 16 + q * 4 + r;
                t[(size_t)m * E_ + e] = (acc[et][r] + oe) * inv[r];
            }
        }
    }
}

// ---------------- fallback K3b: chunk-offset suffix scan + inverse denominators -
__global__ __launch_bounds__(256) void k3b_scan(
        const float* __restrict__ w, const float* __restrict__ chunkTot,
        float* __restrict__ chunkOff, float* __restrict__ invDen) {
    const int tid = threadIdx.x;
    const int b = blockIdx.x;

    float acc = 0.f;
    #pragma unroll
    for (int c = C_ - 1; c >= 0; --c) {
        chunkOff[((size_t)b * C_ + c) * E_ + tid] = acc;
        acc += chunkTot[((size_t)b * C_ + c) * E_ + tid];
    }

    float4 w4 = *(const float4*)(w + b * S_ + tid * 4);
    float tot = w4.x + w4.y + w4.z + w4.w;
    int lane = tid & 63, wv = tid >> 6;
    float suf = tot;
    #pragma unroll
    for (int off = 1; off < 64; off <<= 1) {
        float o = __shfl_down(suf, off, 64);
        if (lane + off < 64) suf += o;
    }
    __shared__ float wsum[4];
    if (lane == 0) wsum[wv] = suf;
    __syncthreads();
    float waveOff = 0.f;
    for (int j = wv + 1; j < 4; ++j) waveOff += wsum[j];
    float after = (suf - tot) + waveOff;
    float s3 = w4.w + after;
    float s2 = w4.z + s3;
    float s1 = w4.y + s2;
    float s0 = w4.x + s1;
    float4 inv = { 1.f / (s0 + 1e-10f), 1.f / (s1 + 1e-10f),
                   1.f / (s2 + 1e-10f), 1.f / (s3 + 1e-10f) };
    *(float4*)(invDen + b * S_ + tid * 4) = inv;
}

// ---------------- fallback K3c: streaming finish ----------------
__global__ __launch_bounds__(256) void k3c_finish(
        float* __restrict__ t, const float* __restrict__ chunkOff,
        const float* __restrict__ invDen) {
    const int blk = blockIdx.x;
    const int b = blk >> 4, c = blk & 15;
    const int tid = threadIdx.x;
    float4* tp = (float4*)(t + ((size_t)b * S_ + c * CS_) * E_);
    const float4* co = (const float4*)(chunkOff + (size_t)blk * E_);
    const float* iv = invDen + b * S_ + c * CS_;
    #pragma unroll
    for (int i = 0; i < 16; ++i) {
        const int idx = i * 256 + tid;
        const int row = idx >> 6;
        const int e4 = idx & 63;
        float4 v = tp[idx];
        float4 o = co[e4];
        float s = iv[row];
        v.x = (v.x + o.x) * s;
        v.y = (v.y + o.y) * s;
        v.z = (v.z + o.z) * s;
        v.w = (v.w + o.w) * s;
        tp[idx] = v;
    }
}

static int g_coop = -1;

extern "C" void kernel_launch(void* const* d_in, const int* in_sizes, int n_in,
                              void* d_out, int out_size, void* d_ws, size_t ws_size,
                              hipStream_t stream) {
    const float* alpha = (const float*)d_in[0];
    const float* beta  = (const float*)d_in[1];
    const float* embed = (const float*)d_in[2];
    const float* mask  = (const float*)d_in[3];
    const float* Wb    = (const float*)d_in[4];
    const float* bbp   = (const float*)d_in[5];
    const float* Wa    = (const float*)d_in[6];
    const float* bap   = (const float*)d_in[7];

    float* t = (float*)d_out;

    char* ws = (char*)d_ws;
    float*  chunkTot  = (float*)ws;                                        // 1 MB
    float*  wChunkSum = (float*)(ws + (1 << 20));                          // 16 KB slot
    float*  w         = (float*)(ws + (1 << 20) + (16 << 10));             // 256 KB
    float*  chunkOff  = (float*)(ws + (1 << 20) + (16 << 10) + (256 << 10));   // 1 MB
    float*  invDen    = (float*)(ws + (2 << 20) + (16 << 10) + (256 << 10));   // 256 KB
    __bf16* WbBf      = (__bf16*)(ws + (2 << 20) + (16 << 10) + (512 << 10));  // 128 KB

    if (g_coop < 0) {
        int dev = 0;
        hipGetDevice(&dev);
        int attr = 0;
        hipDeviceGetAttribute(&attr, hipDeviceAttributeCooperativeLaunch, dev);
        int nb = 0;
        hipOccupancyMaxActiveBlocksPerMultiprocessor(&nb, k2_main<true>, 256, 0);
        g_coop = (attr != 0 && nb >= 4) ? 1 : 0;   // need 1024 blocks co-resident
    }

    k0_wb_bf16<<<E_ * H_ / 1024, 256, 0, stream>>>(Wb, WbBf);

    if (g_coop == 1) {
        void* args[] = { (void*)&alpha, (void*)&beta, (void*)&embed, (void*)&mask,
                         (void*)&WbBf, (void*)&bbp, (void*)&Wa, (void*)&bap,
                         (void*)&chunkTot, (void*)&wChunkSum, (void*)&w, (void*)&t };
        hipError_t e = hipLaunchCooperativeKernel(k2_main<true>, dim3(B_ * C_),
                                                  dim3(256), args, 0u, stream);
        if (e == hipSuccess) return;
        g_coop = 0;  // validation failed -> safe 3-kernel path
    }

    k2_main<false><<<B_ * C_, 256, 0, stream>>>(alpha, beta, embed, mask, WbBf, bbp,
                                                Wa, bap, chunkTot, wChunkSum, w, t);
    k3b_scan<<<B_, 256, 0, stream>>>(w, chunkTot, chunkOff, invDen);
    k3c_finish<<<B_ * C_, 256, 0, stream>>>(t, chunkOff, invDen);
}